// Round 11
// baseline (10604.340 us; speedup 1.0000x reference)
//
#include <hip/hip_runtime.h>
#include <math.h>

#define B_  64
#define T_  1024
#define I_  512
#define O_  512
#define NZ  2048      // 4*O
#define KW  1024      // W row stride (I+O)
#define EPS 1e-5f

#define SREC 32       // recurrent grid: 32 blocks, each owns 16 o-values
#define OSL  16

typedef short bf8_t  __attribute__((ext_vector_type(8)));
typedef float f32x4  __attribute__((ext_vector_type(4)));

__device__ __forceinline__ unsigned short f2bf(float f) {
  union { float f; unsigned u; } v; v.f = f;
  unsigned r = v.u + 0x7FFFu + ((v.u >> 16) & 1u);   // RNE
  return (unsigned short)(r >> 16);
}

// ---------------------------------------------------------------------------
// K0: zero flag slots, init h (bf16) from init_hx
// ---------------------------------------------------------------------------
__global__ __launch_bounds__(256) void init_all(
    const float* __restrict__ init_hx,
    unsigned short* __restrict__ h, unsigned* __restrict__ sync) {
  int idx = blockIdx.x * 256 + threadIdx.x;
  if (idx < 2048) sync[idx] = 0u;
  if (idx < B_ * O_) h[idx] = f2bf(init_hx[idx & (O_ - 1)]);
}

// ---------------------------------------------------------------------------
// K0b: one-time x (f32 [64][1024][512]) -> bf16, same layout. ~33 us.
// ---------------------------------------------------------------------------
__global__ __launch_bounds__(256) void x_bf16(
    const float* __restrict__ x, unsigned short* __restrict__ xb) {
  int idx = blockIdx.x * 256 + threadIdx.x;   // one float4 each; 8388608 total
  size_t base = (size_t)idx * 4;
  float4 v = *(const float4*)(x + base);
  unsigned short* d = xb + base;
  d[0] = f2bf(v.x); d[1] = f2bf(v.y); d[2] = f2bf(v.z); d[3] = f2bf(v.w);
}

// ---------------------------------------------------------------------------
// K2: recurrent loop with the x-GEMM FOLDED INTO THE STEP (R11).
// z = x(t)@Wx^T + h(t)@Wh^T computed in one f32 accumulator chain.
//  - Wx slice (64 rows x 512 k) staged in LDS next to Wh (133 KB total;
//    >64KB LDS proven by R10's 75776B block).
//  - x(t+1) fragments prefetched into registers in bar2's shadow (replacing
//    the old zxl prefetch); x-MFMA chain executes BETWEEN h-gather issue and
//    h-use, filling the sc1 gather latency (VALUBusy was 2% — waves idle).
//  - Deletes: zx buffer (256MB write + 256MB read), producers, chunk gates,
//    Wbf. R10's producer MALL traffic cost the consumer ~875us; this version
//    has zero extra MALL traffic.
//  - Sync protocol byte-identical to R7-validated flag scheme (sc1 agent
//    atomics, monotonic flags, 32-line gather poll, syncthreads-drain
//    release). No inline-asm memory ops (R4-6 lesson).
// ---------------------------------------------------------------------------
__global__ __launch_bounds__(256, 1) void lstm_rec(
    const float* __restrict__ W, const float* __restrict__ gamma,
    const float* __restrict__ beta, const float* __restrict__ init_cx,
    const unsigned short* __restrict__ xb, unsigned short* __restrict__ h,
    unsigned long long* __restrict__ part8, float* __restrict__ out,
    unsigned* __restrict__ flags) {

  __shared__ unsigned short whlds[64 * 520];   // Wh rows (g*16+n'), k in [512,1024)
  __shared__ unsigned short wxlds[64 * 520];   // Wx rows (g*16+n'), k in [0,512)

  const int tid  = threadIdx.x;
  const int w    = tid >> 6;
  const int lane = tid & 63;
  const int q    = lane >> 4;
  const int col  = lane & 15;
  const int s    = blockIdx.x;
  const int o    = s * OSL + col;

  // ---- stage Wh + Wx slices -> LDS (once)
  for (int e4 = tid; e4 < 64 * 128; e4 += 256) {
    int r  = e4 >> 7;            // row 0..63
    int k4 = (e4 & 127) * 4;     // k 0..508
    int g  = r >> 4, np = r & 15;
    const float* wrow = W + (size_t)(512 * g + OSL * s + np) * KW;
    const float4 vh = *(const float4*)(wrow + I_ + k4);
    unsigned short* dh = &whlds[r * 520 + k4];
    dh[0] = f2bf(vh.x); dh[1] = f2bf(vh.y); dh[2] = f2bf(vh.z); dh[3] = f2bf(vh.w);
    const float4 vx = *(const float4*)(wrow + k4);
    unsigned short* dx = &wxlds[r * 520 + k4];
    dx[0] = f2bf(vx.x); dx[1] = f2bf(vx.y); dx[2] = f2bf(vx.z); dx[3] = f2bf(vx.w);
  }

  float gma[4], bta[4], c_reg[4];
  #pragma unroll
  for (int g = 0; g < 4; ++g) { gma[g] = gamma[g * O_ + o]; bta[g] = beta[g * O_ + o]; }
  { float c0 = init_cx[o];
    #pragma unroll
    for (int r = 0; r < 4; ++r) c_reg[r] = c0; }

  // ---- prologue: prefetch x fragments for t=0 (plain cached loads)
  unsigned long long xraw[32];
  {
    const unsigned short* xrow = xb + ((size_t)(16 * w + col) * T_ + 0) * I_ + q * 8;
    #pragma unroll
    for (int ks = 0; ks < 16; ++ks) {
      const unsigned long long* p = (const unsigned long long*)(xrow + ks * 32);
      xraw[2 * ks]     = p[0];
      xraw[2 * ks + 1] = p[1];
    }
  }

  __syncthreads();

  for (int t = 0; t < T_; ++t) {
    // ---- issue h-gather (sc1 read-through; fresh after bar2)
    unsigned long long araw[32];
    const unsigned short* hrow = h + (16 * w + col) * O_;
    #pragma unroll
    for (int ks = 0; ks < 16; ++ks) {
      const unsigned long long* p =
          (const unsigned long long*)(hrow + ks * 32 + q * 8);
      araw[2 * ks]     = __hip_atomic_load(p,     __ATOMIC_RELAXED, __HIP_MEMORY_SCOPE_AGENT);
      araw[2 * ks + 1] = __hip_atomic_load(p + 1, __ATOMIC_RELAXED, __HIP_MEMORY_SCOPE_AGENT);
    }

    f32x4 acc[4];
    #pragma unroll
    for (int g = 0; g < 4; ++g) acc[g] = (f32x4){0.f, 0.f, 0.f, 0.f};

    // ---- x-part MFMA chain (independent of h -> overlaps the h gather)
    #pragma unroll
    for (int ks = 0; ks < 16; ++ks) {
      union { unsigned long long u[2]; bf8_t v; } xu;
      xu.u[0] = xraw[2 * ks]; xu.u[1] = xraw[2 * ks + 1];
      #pragma unroll
      for (int g = 0; g < 4; ++g) {
        bf8_t bfr = *(const bf8_t*)(&wxlds[(g * 16 + col) * 520 + ks * 32 + q * 8]);
        acc[g] = __builtin_amdgcn_mfma_f32_16x16x32_bf16(xu.v, bfr, acc[g], 0, 0, 0);
      }
    }

    // ---- h-part MFMA chain (compiler places the vmcnt wait right here)
    #pragma unroll
    for (int ks = 0; ks < 16; ++ks) {
      union { unsigned long long u[2]; bf8_t v; } au;
      au.u[0] = araw[2 * ks]; au.u[1] = araw[2 * ks + 1];
      #pragma unroll
      for (int g = 0; g < 4; ++g) {
        bf8_t bfr = *(const bf8_t*)(&whlds[(g * 16 + col) * 520 + ks * 32 + q * 8]);
        acc[g] = __builtin_amdgcn_mfma_f32_16x16x32_bf16(au.v, bfr, acc[g], 0, 0, 0);
      }
    }

    // ---- z ready in acc; block-partial LN sums per batch row
    float z[16];
    float s1[4], s2[4];
    #pragma unroll
    for (int r = 0; r < 4; ++r) { s1[r] = 0.f; s2[r] = 0.f; }
    #pragma unroll
    for (int g = 0; g < 4; ++g)
      #pragma unroll
      for (int r = 0; r < 4; ++r) {
        float zv = acc[g][r];
        z[g * 4 + r] = zv;
        s1[r] += zv;
        s2[r] += zv * zv;
      }
    #pragma unroll
    for (int m = 1; m < 16; m <<= 1) {
      #pragma unroll
      for (int r = 0; r < 4; ++r) {
        s1[r] += __shfl_xor(s1[r], m, 64);
        s2[r] += __shfl_xor(s2[r], m, 64);
      }
    }
    if (col == 0) {
      #pragma unroll
      for (int r = 0; r < 4; ++r) {
        int b = 16 * w + 4 * q + r;
        union { float f[2]; unsigned long long u; } pv;
        pv.f[0] = s1[r]; pv.f[1] = s2[r];
        __hip_atomic_store(&part8[(size_t)s * 64 + b], pv.u,
                           __ATOMIC_RELAXED, __HIP_MEMORY_SCOPE_AGENT);
      }
    }

    // ---- barrier 1: partials ready
    __syncthreads();   // drains vmcnt(0) for all waves -> partials at LLC
    {
      const unsigned tgt = 2u * (unsigned)t + 1u;
      if (tid == 0)
        __hip_atomic_store(&flags[s * 16], tgt,
                           __ATOMIC_RELAXED, __HIP_MEMORY_SCOPE_AGENT);
      const unsigned* fp = &flags[(tid & 31) * 16];
      while (__hip_atomic_load(fp, __ATOMIC_RELAXED, __HIP_MEMORY_SCOPE_AGENT) < tgt) {}
    }

    // ---- distributed LN reduce: lane owns brow = 16w+(lane&15); 8 s-chunks
    float S1 = 0.f, S2 = 0.f;
    {
      const int brow = 16 * w + (lane & 15);
      const int sbase = (lane >> 4) * 8;
      #pragma unroll
      for (int i = 0; i < 8; ++i) {
        union { float f[2]; unsigned long long u; } pv;
        pv.u = __hip_atomic_load(&part8[(size_t)(sbase + i) * 64 + brow],
                                 __ATOMIC_RELAXED, __HIP_MEMORY_SCOPE_AGENT);
        S1 += pv.f[0]; S2 += pv.f[1];
      }
    }
    S1 += __shfl_xor(S1, 16, 64); S2 += __shfl_xor(S2, 16, 64);
    S1 += __shfl_xor(S1, 32, 64); S2 += __shfl_xor(S2, 32, 64);
    float mean_l = S1 * (1.f / NZ);
    float rstd_l = rsqrtf(S2 * (1.f / NZ) - mean_l * mean_l + EPS);

    // ---- gates + state update (mean/rstd pulled from lane 4q+r)
    float hnl[4];
    #pragma unroll
    for (int r = 0; r < 4; ++r) {
      int b = 16 * w + 4 * q + r;
      float mean = __shfl(mean_l, 4 * q + r, 64);
      float rstd = __shfl(rstd_l, 4 * q + r, 64);
      float zn0 = (z[0 * 4 + r] - mean) * rstd * gma[0] + bta[0];
      float zn1 = (z[1 * 4 + r] - mean) * rstd * gma[1] + bta[1];
      float zn2 = (z[2 * 4 + r] - mean) * rstd * gma[2] + bta[2];
      float zn3 = (z[3 * 4 + r] - mean) * rstd * gma[3] + bta[3];
      float fg = 1.f / (1.f + expf(-zn0));
      float ig = 1.f / (1.f + expf(-zn1));
      float og = 1.f / (1.f + expf(-zn2));
      float gg = 0.5f * zn3 * (1.f + erff(zn3 * 0.70710678118654752f));
      float cn = fg * c_reg[r] + ig * gg;
      float hn = og * cn;
      c_reg[r] = cn;
      hnl[r] = hn;
      __hip_atomic_store(&h[b * O_ + o], f2bf(hn),
                         __ATOMIC_RELAXED, __HIP_MEMORY_SCOPE_AGENT);
    }

    // ---- barrier 2: h ready. out stores + x(t+1) prefetch in the shadow.
    if (t + 1 < T_) {
      __syncthreads();   // drains vmcnt(0) -> h stores at LLC
      const unsigned tgt = 2u * (unsigned)t + 2u;
      if (tid == 0)
        __hip_atomic_store(&flags[s * 16], tgt,
                           __ATOMIC_RELAXED, __HIP_MEMORY_SCOPE_AGENT);
      #pragma unroll
      for (int r = 0; r < 4; ++r) {
        int b = 16 * w + 4 * q + r;
        out[((size_t)b * T_ + t) * O_ + o] = hnl[r];
      }
      {
        const unsigned short* xrow =
            xb + ((size_t)(16 * w + col) * T_ + (t + 1)) * I_ + q * 8;
        #pragma unroll
        for (int ks = 0; ks < 16; ++ks) {
          const unsigned long long* p = (const unsigned long long*)(xrow + ks * 32);
          xraw[2 * ks]     = p[0];
          xraw[2 * ks + 1] = p[1];
        }
      }
      const unsigned* fp = &flags[(tid & 31) * 16];
      while (__hip_atomic_load(fp, __ATOMIC_RELAXED, __HIP_MEMORY_SCOPE_AGENT) < tgt) {}
    } else {
      #pragma unroll
      for (int r = 0; r < 4; ++r) {
        int b = 16 * w + 4 * q + r;
        out[((size_t)b * T_ + t) * O_ + o] = hnl[r];
      }
    }
  }
}

// ---------------------------------------------------------------------------
extern "C" void kernel_launch(void* const* d_in, const int* in_sizes, int n_in,
                              void* d_out, int out_size, void* d_ws, size_t ws_size,
                              hipStream_t stream) {
  const float* x       = (const float*)d_in[0];
  const float* W       = (const float*)d_in[1];
  const float* gamma   = (const float*)d_in[2];
  const float* beta    = (const float*)d_in[3];
  const float* init_hx = (const float*)d_in[4];
  const float* init_cx = (const float*)d_in[5];
  float* out = (float*)d_out;
  (void)in_sizes; (void)n_in; (void)out_size; (void)ws_size;

  char* ws = (char*)d_ws;
  unsigned*           flags = (unsigned*)(ws);                        // 8 KB zeroed
  unsigned long long* part8 = (unsigned long long*)(ws + 8192);       // 16 KB
  unsigned short*     h     = (unsigned short*)(ws + 32768);          // 64 KB
  unsigned short*     xbf   = (unsigned short*)(ws + (1 << 20));      // 64 MB

  init_all<<<128, 256, 0, stream>>>(init_hx, h, flags);
  x_bf16<<<32768, 256, 0, stream>>>(x, xbf);
  lstm_rec<<<SREC, 256, 0, stream>>>(W, gamma, beta, init_cx, xbf, h, part8, out, flags);
}

// Round 12
// 9420.267 us; speedup vs baseline: 1.1257x; 1.1257x over previous
//
#include <hip/hip_runtime.h>
#include <math.h>

#define B_  64
#define T_  1024
#define I_  512
#define O_  512
#define NZ  2048      // 4*O
#define KW  1024      // W row stride (I+O)
#define EPS 1e-5f

#define SREC 32       // recurrent consumer blocks
#define NPROD 1024    // zx producer blocks (one 64-row tile each)
#define OSL  16
#define BAILOUT (1u << 18)

typedef short bf8_t  __attribute__((ext_vector_type(8)));
typedef float f32x4  __attribute__((ext_vector_type(4)));
typedef unsigned uint4v __attribute__((ext_vector_type(4)));

__device__ __forceinline__ unsigned short f2bf(float f) {
  union { float f; unsigned u; } v; v.f = f;
  unsigned r = v.u + 0x7FFFu + ((v.u >> 16) & 1u);   // RNE
  return (unsigned short)(r >> 16);
}
__device__ __forceinline__ float bf2f(unsigned short b) {
  union { unsigned u; float f; } v; v.u = ((unsigned)b) << 16;
  return v.f;
}

// ---------------------------------------------------------------------------
// K0: zero flags (incl. zx chunk counters), init h (bf16) from init_hx
// ---------------------------------------------------------------------------
__global__ __launch_bounds__(256) void init_all(
    const float* __restrict__ init_hx,
    unsigned short* __restrict__ h, unsigned* __restrict__ sync) {
  int idx = blockIdx.x * 256 + threadIdx.x;
  if (idx < 2048) sync[idx] = 0u;
  if (idx < B_ * O_) h[idx] = f2bf(init_hx[idx & (O_ - 1)]);
}

// ---------------------------------------------------------------------------
// K0b: one-time Wx (rows 0..2047, k 0..511) f32 -> bf16.
// ---------------------------------------------------------------------------
__global__ __launch_bounds__(256) void wx_bf16(
    const float* __restrict__ W, unsigned short* __restrict__ Wbf) {
  int idx = blockIdx.x * 256 + threadIdx.x;   // one float4 each; 262144 total
  int n  = idx >> 7;
  int k4 = (idx & 127) * 4;
  float4 v = *(const float4*)(W + (size_t)n * KW + k4);
  unsigned short* d = Wbf + (size_t)n * 512 + k4;
  d[0] = f2bf(v.x); d[1] = f2bf(v.y); d[2] = f2bf(v.z); d[3] = f2bf(v.w);
}

// ---------------------------------------------------------------------------
// FUSED kernel (R10 base): 32 consumer blocks (R7-validated lstm_rec) +
// 1024 producer blocks (zx tiles, t-chunk-major).
//
// R12 change (ONLY change vs R10): POLL CONCENTRATION at bar1/bar2.
//  - Previously all 128 consumer waves continuously issued 32-line gather
//    polls (~213 gathers/us hammering the 32 flag lines the arriving flag
//    stores must beat in LLC bank arbitration). Now only WAVE 0 polls
//    (lane l watches flags[(l&31)*16], s_sleep(1) backoff); waves 1-3 are
//    released by __syncthreads. 4x less poll pressure on the MALL.
//  - Certificate semantics unchanged: writer-side drain+flag protocol is
//    byte-identical; readers' sc1 loads still go to the coherence point.
// ---------------------------------------------------------------------------
__global__ __launch_bounds__(256) void fused_rec(
    const float* __restrict__ x, const unsigned short* __restrict__ Wbf,
    const float* __restrict__ W, const float* __restrict__ gamma,
    const float* __restrict__ beta, const float* __restrict__ init_cx,
    unsigned short* __restrict__ zx, unsigned short* __restrict__ h,
    unsigned long long* __restrict__ part8, float* __restrict__ out,
    unsigned* __restrict__ flags) {

  __shared__ unsigned short smem[37888];

  const int tid  = threadIdx.x;
  const int w    = tid >> 6;
  const int lane = tid & 63;
  const int q    = lane >> 4;
  const int col  = lane & 15;
  unsigned* zxcnt = flags + 1024;   // 16 chunk counters (zeroed by init_all)

  if (blockIdx.x >= SREC) {
    // =============== PRODUCER: one 64-row zx tile (R10 verbatim) =========
    const int p  = blockIdx.x - SREC;       // 0..1023
    const int b  = p & 63;                  // batch
    const int tc = p >> 6;                  // t-chunk 0..15
    const int m0 = b * T_ + tc * 64;        // first row of tile

    unsigned short* xl  = smem;             // [64][520]
    unsigned short* cst = smem + 33280;     // [64][72]

    for (int e4 = tid; e4 < 64 * 128; e4 += 256) {
      int r  = e4 >> 7;
      int k4 = (e4 & 127) * 4;
      float4 v = *(const float4*)(x + (size_t)(m0 + r) * I_ + k4);
      unsigned short* d = &xl[r * 520 + k4];
      d[0] = f2bf(v.x); d[1] = f2bf(v.y); d[2] = f2bf(v.z); d[3] = f2bf(v.w);
    }
    __syncthreads();

    const unsigned short* arow = &xl[(16 * w + col) * 520];
    const int crow = tid >> 2;
    const int cc0  = (tid & 3) * 16;

    for (int nblk = 0; nblk < 32; ++nblk) {
      const int n0 = nblk * 64;
      f32x4 acc[4];
      #pragma unroll
      for (int i = 0; i < 4; ++i) acc[i] = (f32x4){0.f, 0.f, 0.f, 0.f};

      #pragma unroll
      for (int ks = 0; ks < 16; ++ks) {
        const int k0 = ks * 32 + q * 8;
        bf8_t af = *(const bf8_t*)(arow + k0);
        #pragma unroll
        for (int nt = 0; nt < 4; ++nt) {
          bf8_t bfr = *(const bf8_t*)(Wbf + (size_t)(n0 + nt * 16 + col) * 512 + k0);
          acc[nt] = __builtin_amdgcn_mfma_f32_16x16x32_bf16(af, bfr, acc[nt], 0, 0, 0);
        }
      }
      __syncthreads();
      #pragma unroll
      for (int nt = 0; nt < 4; ++nt)
        #pragma unroll
        for (int r = 0; r < 4; ++r)
          cst[(16 * w + 4 * q + r) * 72 + nt * 16 + col] = f2bf(acc[nt][r]);
      __syncthreads();
      {
        union { uint4v v; unsigned long long u[2]; } a0, a1;
        const uint4v* srcp = (const uint4v*)&cst[crow * 72 + cc0];
        a0.v = srcp[0]; a1.v = srcp[1];
        unsigned long long* dst =
            (unsigned long long*)&zx[(size_t)(m0 + crow) * NZ + n0 + cc0];
        __hip_atomic_store(dst + 0, a0.u[0], __ATOMIC_RELAXED, __HIP_MEMORY_SCOPE_AGENT);
        __hip_atomic_store(dst + 1, a0.u[1], __ATOMIC_RELAXED, __HIP_MEMORY_SCOPE_AGENT);
        __hip_atomic_store(dst + 2, a1.u[0], __ATOMIC_RELAXED, __HIP_MEMORY_SCOPE_AGENT);
        __hip_atomic_store(dst + 3, a1.u[1], __ATOMIC_RELAXED, __HIP_MEMORY_SCOPE_AGENT);
      }
    }
    __syncthreads();   // drains vmcnt(0) for all waves -> tile at LLC
    if (tid == 0)
      __hip_atomic_fetch_add(&zxcnt[tc], 1u, __ATOMIC_RELAXED,
                             __HIP_MEMORY_SCOPE_AGENT);
    return;
  }

  // =============== CONSUMER: R7-validated recurrent loop ================
  unsigned short* whlds = smem;   // [64][520]
  const int s = blockIdx.x;
  const int o = s * OSL + col;

  // ---- stage Wh slice -> LDS (once)
  for (int e4 = tid; e4 < 64 * 128; e4 += 256) {
    int r  = e4 >> 7;
    int k4 = (e4 & 127) * 4;
    int g  = r >> 4, np = r & 15;
    const float4 v =
        *(const float4*)(W + (size_t)(512 * g + OSL * s + np) * KW + I_ + k4);
    unsigned short* d = &whlds[r * 520 + k4];
    d[0] = f2bf(v.x); d[1] = f2bf(v.y); d[2] = f2bf(v.z); d[3] = f2bf(v.w);
  }

  float gma[4], bta[4], c_reg[4];
  #pragma unroll
  for (int g = 0; g < 4; ++g) { gma[g] = gamma[g * O_ + o]; bta[g] = beta[g * O_ + o]; }
  { float c0 = init_cx[o];
    #pragma unroll
    for (int r = 0; r < 4; ++r) c_reg[r] = c0; }

  // ---- prologue: wait for zx chunk 0, then prefetch zx for t=0
  {
    unsigned spins = 0;
    while (__hip_atomic_load(&zxcnt[0], __ATOMIC_RELAXED,
                             __HIP_MEMORY_SCOPE_AGENT) < 64u) {
      __builtin_amdgcn_s_sleep(2);
      if (++spins > BAILOUT) break;
    }
  }
  unsigned short zxl[16];
  #pragma unroll
  for (int g = 0; g < 4; ++g)
    #pragma unroll
    for (int r = 0; r < 4; ++r) {
      int b = 16 * w + 4 * q + r;
      zxl[g * 4 + r] = zx[((size_t)b * T_ + 0) * NZ + g * O_ + OSL * s + col];
    }

  __syncthreads();

  for (int t = 0; t < T_; ++t) {
    // ---- gather full h fragment set (sc1 read-through; fresh after bar2)
    unsigned long long araw[32];
    const unsigned short* hrow = h + (16 * w + col) * O_;
    #pragma unroll
    for (int ks = 0; ks < 16; ++ks) {
      const unsigned long long* p =
          (const unsigned long long*)(hrow + ks * 32 + q * 8);
      araw[2 * ks]     = __hip_atomic_load(p,     __ATOMIC_RELAXED, __HIP_MEMORY_SCOPE_AGENT);
      araw[2 * ks + 1] = __hip_atomic_load(p + 1, __ATOMIC_RELAXED, __HIP_MEMORY_SCOPE_AGENT);
    }

    // ---- z-slice = h @ Wh^T  (16x16x32 bf16 MFMA; Wh from LDS)
    f32x4 acc[4];
    #pragma unroll
    for (int g = 0; g < 4; ++g) acc[g] = (f32x4){0.f, 0.f, 0.f, 0.f};

    #pragma unroll
    for (int ks = 0; ks < 16; ++ks) {
      union { unsigned long long u[2]; bf8_t v; } au;
      au.u[0] = araw[2 * ks]; au.u[1] = araw[2 * ks + 1];
      #pragma unroll
      for (int g = 0; g < 4; ++g) {
        bf8_t bfr = *(const bf8_t*)(&whlds[(g * 16 + col) * 520 + ks * 32 + q * 8]);
        acc[g] = __builtin_amdgcn_mfma_f32_16x16x32_bf16(au.v, bfr, acc[g], 0, 0, 0);
      }
    }

    // ---- z = acc + zx; block-partial LN sums per batch row
    float z[16];
    float s1[4], s2[4];
    #pragma unroll
    for (int r = 0; r < 4; ++r) { s1[r] = 0.f; s2[r] = 0.f; }
    #pragma unroll
    for (int g = 0; g < 4; ++g)
      #pragma unroll
      for (int r = 0; r < 4; ++r) {
        float zv = acc[g][r] + bf2f(zxl[g * 4 + r]);
        z[g * 4 + r] = zv;
        s1[r] += zv;
        s2[r] += zv * zv;
      }
    #pragma unroll
    for (int m = 1; m < 16; m <<= 1) {
      #pragma unroll
      for (int r = 0; r < 4; ++r) {
        s1[r] += __shfl_xor(s1[r], m, 64);
        s2[r] += __shfl_xor(s2[r], m, 64);
      }
    }
    if (col == 0) {
      #pragma unroll
      for (int r = 0; r < 4; ++r) {
        int b = 16 * w + 4 * q + r;
        union { float f[2]; unsigned long long u; } pv;
        pv.f[0] = s1[r]; pv.f[1] = s2[r];
        __hip_atomic_store(&part8[(size_t)s * 64 + b], pv.u,
                           __ATOMIC_RELAXED, __HIP_MEMORY_SCOPE_AGENT);
      }
    }

    // ---- barrier 1: partials ready (wave0-only poll + fan-out)
    __syncthreads();   // drains vmcnt(0) for all waves -> partials at LLC
    {
      const unsigned tgt = 2u * (unsigned)t + 1u;
      if (tid == 0)
        __hip_atomic_store(&flags[s * 16], tgt,
                           __ATOMIC_RELAXED, __HIP_MEMORY_SCOPE_AGENT);
      if (tid < 64) {
        const unsigned* fp = &flags[(lane & 31) * 16];
        while (__hip_atomic_load(fp, __ATOMIC_RELAXED, __HIP_MEMORY_SCOPE_AGENT) < tgt)
          __builtin_amdgcn_s_sleep(1);
      }
      __syncthreads();
    }

    // ---- distributed LN reduce: lane owns brow = 16w+(lane&15); 8 s-chunks
    float S1 = 0.f, S2 = 0.f;
    {
      const int brow = 16 * w + (lane & 15);
      const int sbase = (lane >> 4) * 8;
      #pragma unroll
      for (int i = 0; i < 8; ++i) {
        union { float f[2]; unsigned long long u; } pv;
        pv.u = __hip_atomic_load(&part8[(size_t)(sbase + i) * 64 + brow],
                                 __ATOMIC_RELAXED, __HIP_MEMORY_SCOPE_AGENT);
        S1 += pv.f[0]; S2 += pv.f[1];
      }
    }
    S1 += __shfl_xor(S1, 16, 64); S2 += __shfl_xor(S2, 16, 64);
    S1 += __shfl_xor(S1, 32, 64); S2 += __shfl_xor(S2, 32, 64);
    float mean_l = S1 * (1.f / NZ);
    float rstd_l = rsqrtf(S2 * (1.f / NZ) - mean_l * mean_l + EPS);

    // ---- gates + state update (mean/rstd pulled from lane 4q+r)
    float hnl[4];
    #pragma unroll
    for (int r = 0; r < 4; ++r) {
      int b = 16 * w + 4 * q + r;
      float mean = __shfl(mean_l, 4 * q + r, 64);
      float rstd = __shfl(rstd_l, 4 * q + r, 64);
      float zn0 = (z[0 * 4 + r] - mean) * rstd * gma[0] + bta[0];
      float zn1 = (z[1 * 4 + r] - mean) * rstd * gma[1] + bta[1];
      float zn2 = (z[2 * 4 + r] - mean) * rstd * gma[2] + bta[2];
      float zn3 = (z[3 * 4 + r] - mean) * rstd * gma[3] + bta[3];
      float fg = 1.f / (1.f + expf(-zn0));
      float ig = 1.f / (1.f + expf(-zn1));
      float og = 1.f / (1.f + expf(-zn2));
      float gg = 0.5f * zn3 * (1.f + erff(zn3 * 0.70710678118654752f));
      float cn = fg * c_reg[r] + ig * gg;
      float hn = og * cn;
      c_reg[r] = cn;
      hnl[r] = hn;
      __hip_atomic_store(&h[b * O_ + o], f2bf(hn),
                         __ATOMIC_RELAXED, __HIP_MEMORY_SCOPE_AGENT);
    }

    // ---- barrier 2: h ready. out stores + zx prefetch in the shadow;
    //      wave0-only poll + fan-out.
    if (t + 1 < T_) {
      __syncthreads();   // drains vmcnt(0) -> h stores at LLC
      const unsigned tgt = 2u * (unsigned)t + 2u;
      if (tid == 0)
        __hip_atomic_store(&flags[s * 16], tgt,
                           __ATOMIC_RELAXED, __HIP_MEMORY_SCOPE_AGENT);
      #pragma unroll
      for (int r = 0; r < 4; ++r) {
        int b = 16 * w + 4 * q + r;
        out[((size_t)b * T_ + t) * O_ + o] = hnl[r];
      }
      // gate on producer chunk at chunk boundaries, then prefetch zx(t+1)
      if (((t + 1) & 63) == 0) {
        const int tc = (t + 1) >> 6;
        unsigned spins = 0;
        while (__hip_atomic_load(&zxcnt[tc], __ATOMIC_RELAXED,
                                 __HIP_MEMORY_SCOPE_AGENT) < 64u) {
          __builtin_amdgcn_s_sleep(2);
          if (++spins > BAILOUT) break;
        }
      }
      #pragma unroll
      for (int g = 0; g < 4; ++g)
        #pragma unroll
        for (int r = 0; r < 4; ++r) {
          int b = 16 * w + 4 * q + r;
          zxl[g * 4 + r] =
              zx[((size_t)b * T_ + (t + 1)) * NZ + g * O_ + OSL * s + col];
        }
      if (tid < 64) {
        const unsigned* fp = &flags[(lane & 31) * 16];
        while (__hip_atomic_load(fp, __ATOMIC_RELAXED, __HIP_MEMORY_SCOPE_AGENT) < tgt)
          __builtin_amdgcn_s_sleep(1);
      }
      __syncthreads();
    } else {
      #pragma unroll
      for (int r = 0; r < 4; ++r) {
        int b = 16 * w + 4 * q + r;
        out[((size_t)b * T_ + t) * O_ + o] = hnl[r];
      }
    }
  }
}

// ---------------------------------------------------------------------------
extern "C" void kernel_launch(void* const* d_in, const int* in_sizes, int n_in,
                              void* d_out, int out_size, void* d_ws, size_t ws_size,
                              hipStream_t stream) {
  const float* x       = (const float*)d_in[0];
  const float* W       = (const float*)d_in[1];
  const float* gamma   = (const float*)d_in[2];
  const float* beta    = (const float*)d_in[3];
  const float* init_hx = (const float*)d_in[4];
  const float* init_cx = (const float*)d_in[5];
  float* out = (float*)d_out;
  (void)in_sizes; (void)n_in; (void)out_size; (void)ws_size;

  char* ws = (char*)d_ws;
  unsigned*           flags = (unsigned*)(ws);                        // 8 KB zeroed (incl zxcnt @ +4KB)
  unsigned long long* part8 = (unsigned long long*)(ws + 8192);       // 16 KB
  unsigned short*     h     = (unsigned short*)(ws + 32768);          // 64 KB
  unsigned short*     Wbf   = (unsigned short*)(ws + (1 << 20));      // 2 MB
  unsigned short*     zx    = (unsigned short*)(ws + (4 << 20));      // 256 MB

  init_all<<<128, 256, 0, stream>>>(init_hx, h, flags);
  wx_bf16<<<1024, 256, 0, stream>>>(W, Wbf);
  fused_rec<<<SREC + NPROD, 256, 0, stream>>>(x, Wbf, W, gamma, beta, init_cx,
                                              zx, h, part8, out, flags);
}

// Round 13
// 8887.110 us; speedup vs baseline: 1.1932x; 1.0600x over previous
//
#include <hip/hip_runtime.h>
#include <math.h>

#define B_  64
#define T_  1024
#define I_  512
#define O_  512
#define NZ  2048      // 4*O
#define KW  1024      // W row stride (I+O)
#define EPS 1e-5f

#define SREC 32       // recurrent consumer blocks
#define NPROD 1024    // zx producer blocks (one 64-row tile each)
#define OSL  16
#define BAILOUT (1u << 18)
#define RING 4        // zx ring slots (chunks); 4 x 16 MB = 64 MB, MALL-resident

typedef short bf8_t  __attribute__((ext_vector_type(8)));
typedef float f32x4  __attribute__((ext_vector_type(4)));
typedef unsigned uint4v __attribute__((ext_vector_type(4)));

__device__ __forceinline__ unsigned short f2bf(float f) {
  union { float f; unsigned u; } v; v.f = f;
  unsigned r = v.u + 0x7FFFu + ((v.u >> 16) & 1u);   // RNE
  return (unsigned short)(r >> 16);
}
__device__ __forceinline__ float bf2f(unsigned short b) {
  union { unsigned u; float f; } v; v.u = ((unsigned)b) << 16;
  return v.f;
}
// ring row index for (batch b, timestep t): slot-major
__device__ __forceinline__ size_t zx_row(int b, int t) {
  return (size_t)(((t >> 6) & (RING - 1)) * 64 + b) * 64 + (t & 63);
}

// ---------------------------------------------------------------------------
// K0: zero flags (incl. zxcnt + progress), init h (bf16) from init_hx
// ---------------------------------------------------------------------------
__global__ __launch_bounds__(256) void init_all(
    const float* __restrict__ init_hx,
    unsigned short* __restrict__ h, unsigned* __restrict__ sync) {
  int idx = blockIdx.x * 256 + threadIdx.x;
  if (idx < 2048) sync[idx] = 0u;
  if (idx < B_ * O_) h[idx] = f2bf(init_hx[idx & (O_ - 1)]);
}

// ---------------------------------------------------------------------------
// K0b: one-time Wx (rows 0..2047, k 0..511) f32 -> bf16.
// ---------------------------------------------------------------------------
__global__ __launch_bounds__(256) void wx_bf16(
    const float* __restrict__ W, unsigned short* __restrict__ Wbf) {
  int idx = blockIdx.x * 256 + threadIdx.x;   // one float4 each; 262144 total
  int n  = idx >> 7;
  int k4 = (idx & 127) * 4;
  float4 v = *(const float4*)(W + (size_t)n * KW + k4);
  unsigned short* d = Wbf + (size_t)n * 512 + k4;
  d[0] = f2bf(v.x); d[1] = f2bf(v.y); d[2] = f2bf(v.z); d[3] = f2bf(v.w);
}

// ---------------------------------------------------------------------------
// FUSED kernel (R12 base). R13 change: zx is a 4-chunk RING BUFFER with
// producer flow control, instead of a 256 MB one-shot buffer.
//  - R12's counters showed MALL thrash: WRITE_SIZE 1.31 GB (zx spilling to
//    HBM; producers finish all 16 chunks ~10x faster than consumption) and
//    the eviction traffic slowed the consumer +0.8us/step vs solo R7.
//  - Ring = 64 MB, MALL-resident. Producer of chunk c (c>=4) waits until
//    consumers finished READING chunk c-4: consumer block 0 publishes
//    progress=2t+2 after its bar2(t) poll (proves all flags >= 2t+2); chunk
//    c-4's last zx read precedes flag 2*((c-4)*64+63)+1, so gate =
//    progress >= that. Producers poll ONE line with s_sleep(64) backoff.
//  - Consumers read ring slots with sc1 u32 loads (addresses reused ->
//    plain cached reads could serve stale chunk c-4 data).
//  - All gates have bailouts: fail-with-data, never hang.
// ---------------------------------------------------------------------------
__global__ __launch_bounds__(256) void fused_rec(
    const float* __restrict__ x, const unsigned short* __restrict__ Wbf,
    const float* __restrict__ W, const float* __restrict__ gamma,
    const float* __restrict__ beta, const float* __restrict__ init_cx,
    unsigned short* __restrict__ zx, unsigned short* __restrict__ h,
    unsigned long long* __restrict__ part8, float* __restrict__ out,
    unsigned* __restrict__ flags) {

  __shared__ unsigned short smem[37888];

  const int tid  = threadIdx.x;
  const int w    = tid >> 6;
  const int lane = tid & 63;
  const int q    = lane >> 4;
  const int col  = lane & 15;
  unsigned* zxcnt    = flags + 1024;   // 16 chunk counters
  unsigned* progress = flags + 768;    // consumer progress (block 0 publishes)

  if (blockIdx.x >= SREC) {
    // =============== PRODUCER: one 64-row zx tile =======================
    const int p   = blockIdx.x - SREC;      // 0..1023
    const int b   = p & 63;                 // batch
    const int tc  = p >> 6;                 // t-chunk 0..15
    const int m0x = b * T_ + tc * 64;       // x rows (source)
    const int m0z = ((tc & (RING - 1)) * 64 + b) * 64;   // ring rows (dest)

    // ---- flow-control gate: slot must be fully consumed (chunk tc-4 read)
    if (tc >= RING) {
      const unsigned gate = 2u * (unsigned)((tc - RING) * 64 + 63) + 1u;
      if (tid == 0) {
        unsigned spins = 0;
        while (__hip_atomic_load(progress, __ATOMIC_RELAXED,
                                 __HIP_MEMORY_SCOPE_AGENT) < gate) {
          __builtin_amdgcn_s_sleep(64);
          if (++spins > BAILOUT) break;
        }
      }
      __syncthreads();
    }

    unsigned short* xl  = smem;             // [64][520]
    unsigned short* cst = smem + 33280;     // [64][72]

    for (int e4 = tid; e4 < 64 * 128; e4 += 256) {
      int r  = e4 >> 7;
      int k4 = (e4 & 127) * 4;
      float4 v = *(const float4*)(x + (size_t)(m0x + r) * I_ + k4);
      unsigned short* d = &xl[r * 520 + k4];
      d[0] = f2bf(v.x); d[1] = f2bf(v.y); d[2] = f2bf(v.z); d[3] = f2bf(v.w);
    }
    __syncthreads();

    const unsigned short* arow = &xl[(16 * w + col) * 520];
    const int crow = tid >> 2;
    const int cc0  = (tid & 3) * 16;

    for (int nblk = 0; nblk < 32; ++nblk) {
      const int n0 = nblk * 64;
      f32x4 acc[4];
      #pragma unroll
      for (int i = 0; i < 4; ++i) acc[i] = (f32x4){0.f, 0.f, 0.f, 0.f};

      #pragma unroll
      for (int ks = 0; ks < 16; ++ks) {
        const int k0 = ks * 32 + q * 8;
        bf8_t af = *(const bf8_t*)(arow + k0);
        #pragma unroll
        for (int nt = 0; nt < 4; ++nt) {
          bf8_t bfr = *(const bf8_t*)(Wbf + (size_t)(n0 + nt * 16 + col) * 512 + k0);
          acc[nt] = __builtin_amdgcn_mfma_f32_16x16x32_bf16(af, bfr, acc[nt], 0, 0, 0);
        }
      }
      __syncthreads();
      #pragma unroll
      for (int nt = 0; nt < 4; ++nt)
        #pragma unroll
        for (int r = 0; r < 4; ++r)
          cst[(16 * w + 4 * q + r) * 72 + nt * 16 + col] = f2bf(acc[nt][r]);
      __syncthreads();
      {
        union { uint4v v; unsigned long long u[2]; } a0, a1;
        const uint4v* srcp = (const uint4v*)&cst[crow * 72 + cc0];
        a0.v = srcp[0]; a1.v = srcp[1];
        unsigned long long* dst =
            (unsigned long long*)&zx[(size_t)(m0z + crow) * NZ + n0 + cc0];
        __hip_atomic_store(dst + 0, a0.u[0], __ATOMIC_RELAXED, __HIP_MEMORY_SCOPE_AGENT);
        __hip_atomic_store(dst + 1, a0.u[1], __ATOMIC_RELAXED, __HIP_MEMORY_SCOPE_AGENT);
        __hip_atomic_store(dst + 2, a1.u[0], __ATOMIC_RELAXED, __HIP_MEMORY_SCOPE_AGENT);
        __hip_atomic_store(dst + 3, a1.u[1], __ATOMIC_RELAXED, __HIP_MEMORY_SCOPE_AGENT);
      }
    }
    __syncthreads();   // drains vmcnt(0) for all waves -> tile at LLC
    if (tid == 0)
      __hip_atomic_fetch_add(&zxcnt[tc], 1u, __ATOMIC_RELAXED,
                             __HIP_MEMORY_SCOPE_AGENT);
    return;
  }

  // =============== CONSUMER: R7-validated recurrent loop ================
  unsigned short* whlds = smem;   // [64][520]
  const int s = blockIdx.x;
  const int o = s * OSL + col;

  // ---- stage Wh slice -> LDS (once)
  for (int e4 = tid; e4 < 64 * 128; e4 += 256) {
    int r  = e4 >> 7;
    int k4 = (e4 & 127) * 4;
    int g  = r >> 4, np = r & 15;
    const float4 v =
        *(const float4*)(W + (size_t)(512 * g + OSL * s + np) * KW + I_ + k4);
    unsigned short* d = &whlds[r * 520 + k4];
    d[0] = f2bf(v.x); d[1] = f2bf(v.y); d[2] = f2bf(v.z); d[3] = f2bf(v.w);
  }

  float gma[4], bta[4], c_reg[4];
  #pragma unroll
  for (int g = 0; g < 4; ++g) { gma[g] = gamma[g * O_ + o]; bta[g] = beta[g * O_ + o]; }
  { float c0 = init_cx[o];
    #pragma unroll
    for (int r = 0; r < 4; ++r) c_reg[r] = c0; }

  // ---- zx ring read helper state: lane reads u32 word containing its 2B
  // (sc1: slot addresses are reused across chunks -> must bypass caches)
  const int wsel = col & 1;            // which half of the u32
  const int widx = col >> 1;           // u32 index within 16-col group

  // ---- prologue: wait for zx chunk 0, then prefetch zx for t=0
  {
    unsigned spins = 0;
    while (__hip_atomic_load(&zxcnt[0], __ATOMIC_RELAXED,
                             __HIP_MEMORY_SCOPE_AGENT) < 64u) {
      __builtin_amdgcn_s_sleep(2);
      if (++spins > BAILOUT) break;
    }
  }
  unsigned short zxl[16];
  #pragma unroll
  for (int g = 0; g < 4; ++g)
    #pragma unroll
    for (int r = 0; r < 4; ++r) {
      int b = 16 * w + 4 * q + r;
      const unsigned* rowp =
          (const unsigned*)(zx + zx_row(b, 0) * NZ + g * O_ + OSL * s);
      unsigned vw = __hip_atomic_load(rowp + widx, __ATOMIC_RELAXED,
                                      __HIP_MEMORY_SCOPE_AGENT);
      zxl[g * 4 + r] = (unsigned short)(wsel ? (vw >> 16) : (vw & 0xffffu));
    }

  __syncthreads();

  for (int t = 0; t < T_; ++t) {
    // ---- gather full h fragment set (sc1 read-through; fresh after bar2)
    unsigned long long araw[32];
    const unsigned short* hrow = h + (16 * w + col) * O_;
    #pragma unroll
    for (int ks = 0; ks < 16; ++ks) {
      const unsigned long long* p =
          (const unsigned long long*)(hrow + ks * 32 + q * 8);
      araw[2 * ks]     = __hip_atomic_load(p,     __ATOMIC_RELAXED, __HIP_MEMORY_SCOPE_AGENT);
      araw[2 * ks + 1] = __hip_atomic_load(p + 1, __ATOMIC_RELAXED, __HIP_MEMORY_SCOPE_AGENT);
    }

    // ---- z-slice = h @ Wh^T  (16x16x32 bf16 MFMA; Wh from LDS)
    f32x4 acc[4];
    #pragma unroll
    for (int g = 0; g < 4; ++g) acc[g] = (f32x4){0.f, 0.f, 0.f, 0.f};

    #pragma unroll
    for (int ks = 0; ks < 16; ++ks) {
      union { unsigned long long u[2]; bf8_t v; } au;
      au.u[0] = araw[2 * ks]; au.u[1] = araw[2 * ks + 1];
      #pragma unroll
      for (int g = 0; g < 4; ++g) {
        bf8_t bfr = *(const bf8_t*)(&whlds[(g * 16 + col) * 520 + ks * 32 + q * 8]);
        acc[g] = __builtin_amdgcn_mfma_f32_16x16x32_bf16(au.v, bfr, acc[g], 0, 0, 0);
      }
    }

    // ---- z = acc + zx; block-partial LN sums per batch row
    float z[16];
    float s1[4], s2[4];
    #pragma unroll
    for (int r = 0; r < 4; ++r) { s1[r] = 0.f; s2[r] = 0.f; }
    #pragma unroll
    for (int g = 0; g < 4; ++g)
      #pragma unroll
      for (int r = 0; r < 4; ++r) {
        float zv = acc[g][r] + bf2f(zxl[g * 4 + r]);
        z[g * 4 + r] = zv;
        s1[r] += zv;
        s2[r] += zv * zv;
      }
    #pragma unroll
    for (int m = 1; m < 16; m <<= 1) {
      #pragma unroll
      for (int r = 0; r < 4; ++r) {
        s1[r] += __shfl_xor(s1[r], m, 64);
        s2[r] += __shfl_xor(s2[r], m, 64);
      }
    }
    if (col == 0) {
      #pragma unroll
      for (int r = 0; r < 4; ++r) {
        int b = 16 * w + 4 * q + r;
        union { float f[2]; unsigned long long u; } pv;
        pv.f[0] = s1[r]; pv.f[1] = s2[r];
        __hip_atomic_store(&part8[(size_t)s * 64 + b], pv.u,
                           __ATOMIC_RELAXED, __HIP_MEMORY_SCOPE_AGENT);
      }
    }

    // ---- barrier 1: partials ready (wave0-only poll + fan-out)
    __syncthreads();   // drains vmcnt(0) for all waves -> partials at LLC
    {
      const unsigned tgt = 2u * (unsigned)t + 1u;
      if (tid == 0)
        __hip_atomic_store(&flags[s * 16], tgt,
                           __ATOMIC_RELAXED, __HIP_MEMORY_SCOPE_AGENT);
      if (tid < 64) {
        const unsigned* fp = &flags[(lane & 31) * 16];
        while (__hip_atomic_load(fp, __ATOMIC_RELAXED, __HIP_MEMORY_SCOPE_AGENT) < tgt)
          __builtin_amdgcn_s_sleep(1);
      }
      __syncthreads();
    }

    // ---- distributed LN reduce: lane owns brow = 16w+(lane&15); 8 s-chunks
    float S1 = 0.f, S2 = 0.f;
    {
      const int brow = 16 * w + (lane & 15);
      const int sbase = (lane >> 4) * 8;
      #pragma unroll
      for (int i = 0; i < 8; ++i) {
        union { float f[2]; unsigned long long u; } pv;
        pv.u = __hip_atomic_load(&part8[(size_t)(sbase + i) * 64 + brow],
                                 __ATOMIC_RELAXED, __HIP_MEMORY_SCOPE_AGENT);
        S1 += pv.f[0]; S2 += pv.f[1];
      }
    }
    S1 += __shfl_xor(S1, 16, 64); S2 += __shfl_xor(S2, 16, 64);
    S1 += __shfl_xor(S1, 32, 64); S2 += __shfl_xor(S2, 32, 64);
    float mean_l = S1 * (1.f / NZ);
    float rstd_l = rsqrtf(S2 * (1.f / NZ) - mean_l * mean_l + EPS);

    // ---- gates + state update (mean/rstd pulled from lane 4q+r)
    float hnl[4];
    #pragma unroll
    for (int r = 0; r < 4; ++r) {
      int b = 16 * w + 4 * q + r;
      float mean = __shfl(mean_l, 4 * q + r, 64);
      float rstd = __shfl(rstd_l, 4 * q + r, 64);
      float zn0 = (z[0 * 4 + r] - mean) * rstd * gma[0] + bta[0];
      float zn1 = (z[1 * 4 + r] - mean) * rstd * gma[1] + bta[1];
      float zn2 = (z[2 * 4 + r] - mean) * rstd * gma[2] + bta[2];
      float zn3 = (z[3 * 4 + r] - mean) * rstd * gma[3] + bta[3];
      float fg = 1.f / (1.f + expf(-zn0));
      float ig = 1.f / (1.f + expf(-zn1));
      float og = 1.f / (1.f + expf(-zn2));
      float gg = 0.5f * zn3 * (1.f + erff(zn3 * 0.70710678118654752f));
      float cn = fg * c_reg[r] + ig * gg;
      float hn = og * cn;
      c_reg[r] = cn;
      hnl[r] = hn;
      __hip_atomic_store(&h[b * O_ + o], f2bf(hn),
                         __ATOMIC_RELAXED, __HIP_MEMORY_SCOPE_AGENT);
    }

    // ---- barrier 2: h ready. out stores + zx prefetch in the shadow;
    //      wave0-only poll; block 0 publishes consumer progress after poll.
    if (t + 1 < T_) {
      __syncthreads();   // drains vmcnt(0) -> h stores at LLC
      const unsigned tgt = 2u * (unsigned)t + 2u;
      if (tid == 0)
        __hip_atomic_store(&flags[s * 16], tgt,
                           __ATOMIC_RELAXED, __HIP_MEMORY_SCOPE_AGENT);
      #pragma unroll
      for (int r = 0; r < 4; ++r) {
        int b = 16 * w + 4 * q + r;
        out[((size_t)b * T_ + t) * O_ + o] = hnl[r];
      }
      // gate on producer chunk at chunk boundaries, then prefetch zx(t+1)
      if (((t + 1) & 63) == 0) {
        const int tc = (t + 1) >> 6;
        unsigned spins = 0;
        while (__hip_atomic_load(&zxcnt[tc], __ATOMIC_RELAXED,
                                 __HIP_MEMORY_SCOPE_AGENT) < 64u) {
          __builtin_amdgcn_s_sleep(2);
          if (++spins > BAILOUT) break;
        }
      }
      #pragma unroll
      for (int g = 0; g < 4; ++g)
        #pragma unroll
        for (int r = 0; r < 4; ++r) {
          int b = 16 * w + 4 * q + r;
          const unsigned* rowp =
              (const unsigned*)(zx + zx_row(b, t + 1) * NZ + g * O_ + OSL * s);
          unsigned vw = __hip_atomic_load(rowp + widx, __ATOMIC_RELAXED,
                                          __HIP_MEMORY_SCOPE_AGENT);
          zxl[g * 4 + r] = (unsigned short)(wsel ? (vw >> 16) : (vw & 0xffffu));
        }
      if (tid < 64) {
        const unsigned* fp = &flags[(lane & 31) * 16];
        while (__hip_atomic_load(fp, __ATOMIC_RELAXED, __HIP_MEMORY_SCOPE_AGENT) < tgt)
          __builtin_amdgcn_s_sleep(1);
      }
      if (s == 0 && tid == 0)
        __hip_atomic_store(progress, tgt,
                           __ATOMIC_RELAXED, __HIP_MEMORY_SCOPE_AGENT);
      __syncthreads();
    } else {
      #pragma unroll
      for (int r = 0; r < 4; ++r) {
        int b = 16 * w + 4 * q + r;
        out[((size_t)b * T_ + t) * O_ + o] = hnl[r];
      }
    }
  }
}

// ---------------------------------------------------------------------------
extern "C" void kernel_launch(void* const* d_in, const int* in_sizes, int n_in,
                              void* d_out, int out_size, void* d_ws, size_t ws_size,
                              hipStream_t stream) {
  const float* x       = (const float*)d_in[0];
  const float* W       = (const float*)d_in[1];
  const float* gamma   = (const float*)d_in[2];
  const float* beta    = (const float*)d_in[3];
  const float* init_hx = (const float*)d_in[4];
  const float* init_cx = (const float*)d_in[5];
  float* out = (float*)d_out;
  (void)in_sizes; (void)n_in; (void)out_size; (void)ws_size;

  char* ws = (char*)d_ws;
  unsigned*           flags = (unsigned*)(ws);                        // 8 KB zeroed (zxcnt@+4KB, progress@+3KB)
  unsigned long long* part8 = (unsigned long long*)(ws + 8192);       // 16 KB
  unsigned short*     h     = (unsigned short*)(ws + 32768);          // 64 KB
  unsigned short*     Wbf   = (unsigned short*)(ws + (1 << 20));      // 2 MB
  unsigned short*     zx    = (unsigned short*)(ws + (4 << 20));      // 64 MB ring

  init_all<<<128, 256, 0, stream>>>(init_hx, h, flags);
  wx_bf16<<<1024, 256, 0, stream>>>(W, Wbf);
  fused_rec<<<SREC + NPROD, 256, 0, stream>>>(x, Wbf, W, gamma, beta, init_cx,
                                              zx, h, part8, out, flags);
}

// Round 14
// 8847.810 us; speedup vs baseline: 1.1985x; 1.0044x over previous
//
#include <hip/hip_runtime.h>
#include <math.h>

#define B_  64
#define T_  1024
#define I_  512
#define O_  512
#define NZ  2048      // 4*O
#define KW  1024      // W row stride (I+O)
#define EPS 1e-5f

#define SREC 32       // recurrent consumer blocks
#define NPROD 1024    // zx producer blocks (one 64-row tile each)
#define OSL  16
#define BAILOUT (1u << 18)
#define RING 4        // zx ring slots (chunks); 4 x 16 MB = 64 MB

typedef short bf8_t  __attribute__((ext_vector_type(8)));
typedef float f32x4  __attribute__((ext_vector_type(4)));
typedef unsigned uint4v __attribute__((ext_vector_type(4)));

__device__ __forceinline__ unsigned short f2bf(float f) {
  union { float f; unsigned u; } v; v.f = f;
  unsigned r = v.u + 0x7FFFu + ((v.u >> 16) & 1u);   // RNE
  return (unsigned short)(r >> 16);
}
__device__ __forceinline__ float bf2f(unsigned short b) {
  union { unsigned u; float f; } v; v.u = ((unsigned)b) << 16;
  return v.f;
}
// ring row index for (batch b, timestep t): slot-major
__device__ __forceinline__ size_t zx_row(int b, int t) {
  return (size_t)(((t >> 6) & (RING - 1)) * 64 + b) * 64 + (t & 63);
}

// ---------------------------------------------------------------------------
// K0: zero flags (incl. zxcnt + progress), init h (bf16) from init_hx
// ---------------------------------------------------------------------------
__global__ __launch_bounds__(256) void init_all(
    const float* __restrict__ init_hx,
    unsigned short* __restrict__ h, unsigned* __restrict__ sync) {
  int idx = blockIdx.x * 256 + threadIdx.x;
  if (idx < 2048) sync[idx] = 0u;
  if (idx < B_ * O_) h[idx] = f2bf(init_hx[idx & (O_ - 1)]);
}

// ---------------------------------------------------------------------------
// K0b: one-time Wx (rows 0..2047, k 0..511) f32 -> bf16.
// ---------------------------------------------------------------------------
__global__ __launch_bounds__(256) void wx_bf16(
    const float* __restrict__ W, unsigned short* __restrict__ Wbf) {
  int idx = blockIdx.x * 256 + threadIdx.x;   // one float4 each; 262144 total
  int n  = idx >> 7;
  int k4 = (idx & 127) * 4;
  float4 v = *(const float4*)(W + (size_t)n * KW + k4);
  unsigned short* d = Wbf + (size_t)n * 512 + k4;
  d[0] = f2bf(v.x); d[1] = f2bf(v.y); d[2] = f2bf(v.z); d[3] = f2bf(v.w);
}

// ---------------------------------------------------------------------------
// FUSED kernel (R13 base: ring + flow control). R14 change (ONLY change):
// LDS pool padded to 83200 B (> 160KB/2) -> at most ONE block per CU.
//  - R13's residual 335us vs solo-R7: with 75776B LDS, 2 blocks/CU, so each
//    consumer CU hosted an ACTIVE producer block whose waves stole issue
//    slots / LDS BW / L2 BW on the consumer's latency-critical serial path
//    (Occupancy 15.5% = heavy co-residency).
//  - Now consumers (blockIdx 0-31, dispatched first) own their CUs
//    exclusively; producers cycle through the remaining 224 CUs.
//  - Throughput check: 224 concurrent producer tiles, ~250-400us each, vs
//    consumption of 64 tiles per 545us chunk -> 4-5x margin. Chunks 0-3
//    never gate -> dispatch always drains -> no deadlock.
// ---------------------------------------------------------------------------
__global__ __launch_bounds__(256) void fused_rec(
    const float* __restrict__ x, const unsigned short* __restrict__ Wbf,
    const float* __restrict__ W, const float* __restrict__ gamma,
    const float* __restrict__ beta, const float* __restrict__ init_cx,
    unsigned short* __restrict__ zx, unsigned short* __restrict__ h,
    unsigned long long* __restrict__ part8, float* __restrict__ out,
    unsigned* __restrict__ flags) {

  __shared__ unsigned short smem[41600];   // 83200 B -> 1 block/CU (R14)

  const int tid  = threadIdx.x;
  const int w    = tid >> 6;
  const int lane = tid & 63;
  const int q    = lane >> 4;
  const int col  = lane & 15;
  unsigned* zxcnt    = flags + 1024;   // 16 chunk counters
  unsigned* progress = flags + 768;    // consumer progress (block 0 publishes)

  if (blockIdx.x >= SREC) {
    // =============== PRODUCER: one 64-row zx tile =======================
    const int p   = blockIdx.x - SREC;      // 0..1023
    const int b   = p & 63;                 // batch
    const int tc  = p >> 6;                 // t-chunk 0..15
    const int m0x = b * T_ + tc * 64;       // x rows (source)
    const int m0z = ((tc & (RING - 1)) * 64 + b) * 64;   // ring rows (dest)

    // ---- flow-control gate: slot must be fully consumed (chunk tc-4 read)
    if (tc >= RING) {
      const unsigned gate = 2u * (unsigned)((tc - RING) * 64 + 63) + 1u;
      if (tid == 0) {
        unsigned spins = 0;
        while (__hip_atomic_load(progress, __ATOMIC_RELAXED,
                                 __HIP_MEMORY_SCOPE_AGENT) < gate) {
          __builtin_amdgcn_s_sleep(64);
          if (++spins > BAILOUT) break;
        }
      }
      __syncthreads();
    }

    unsigned short* xl  = smem;             // [64][520]
    unsigned short* cst = smem + 33280;     // [64][72]

    for (int e4 = tid; e4 < 64 * 128; e4 += 256) {
      int r  = e4 >> 7;
      int k4 = (e4 & 127) * 4;
      float4 v = *(const float4*)(x + (size_t)(m0x + r) * I_ + k4);
      unsigned short* d = &xl[r * 520 + k4];
      d[0] = f2bf(v.x); d[1] = f2bf(v.y); d[2] = f2bf(v.z); d[3] = f2bf(v.w);
    }
    __syncthreads();

    const unsigned short* arow = &xl[(16 * w + col) * 520];
    const int crow = tid >> 2;
    const int cc0  = (tid & 3) * 16;

    for (int nblk = 0; nblk < 32; ++nblk) {
      const int n0 = nblk * 64;
      f32x4 acc[4];
      #pragma unroll
      for (int i = 0; i < 4; ++i) acc[i] = (f32x4){0.f, 0.f, 0.f, 0.f};

      #pragma unroll
      for (int ks = 0; ks < 16; ++ks) {
        const int k0 = ks * 32 + q * 8;
        bf8_t af = *(const bf8_t*)(arow + k0);
        #pragma unroll
        for (int nt = 0; nt < 4; ++nt) {
          bf8_t bfr = *(const bf8_t*)(Wbf + (size_t)(n0 + nt * 16 + col) * 512 + k0);
          acc[nt] = __builtin_amdgcn_mfma_f32_16x16x32_bf16(af, bfr, acc[nt], 0, 0, 0);
        }
      }
      __syncthreads();
      #pragma unroll
      for (int nt = 0; nt < 4; ++nt)
        #pragma unroll
        for (int r = 0; r < 4; ++r)
          cst[(16 * w + 4 * q + r) * 72 + nt * 16 + col] = f2bf(acc[nt][r]);
      __syncthreads();
      {
        union { uint4v v; unsigned long long u[2]; } a0, a1;
        const uint4v* srcp = (const uint4v*)&cst[crow * 72 + cc0];
        a0.v = srcp[0]; a1.v = srcp[1];
        unsigned long long* dst =
            (unsigned long long*)&zx[(size_t)(m0z + crow) * NZ + n0 + cc0];
        __hip_atomic_store(dst + 0, a0.u[0], __ATOMIC_RELAXED, __HIP_MEMORY_SCOPE_AGENT);
        __hip_atomic_store(dst + 1, a0.u[1], __ATOMIC_RELAXED, __HIP_MEMORY_SCOPE_AGENT);
        __hip_atomic_store(dst + 2, a1.u[0], __ATOMIC_RELAXED, __HIP_MEMORY_SCOPE_AGENT);
        __hip_atomic_store(dst + 3, a1.u[1], __ATOMIC_RELAXED, __HIP_MEMORY_SCOPE_AGENT);
      }
    }
    __syncthreads();   // drains vmcnt(0) for all waves -> tile at LLC
    if (tid == 0)
      __hip_atomic_fetch_add(&zxcnt[tc], 1u, __ATOMIC_RELAXED,
                             __HIP_MEMORY_SCOPE_AGENT);
    return;
  }

  // =============== CONSUMER: R7-validated recurrent loop ================
  unsigned short* whlds = smem;   // [64][520]
  const int s = blockIdx.x;
  const int o = s * OSL + col;

  // ---- stage Wh slice -> LDS (once)
  for (int e4 = tid; e4 < 64 * 128; e4 += 256) {
    int r  = e4 >> 7;
    int k4 = (e4 & 127) * 4;
    int g  = r >> 4, np = r & 15;
    const float4 v =
        *(const float4*)(W + (size_t)(512 * g + OSL * s + np) * KW + I_ + k4);
    unsigned short* d = &whlds[r * 520 + k4];
    d[0] = f2bf(v.x); d[1] = f2bf(v.y); d[2] = f2bf(v.z); d[3] = f2bf(v.w);
  }

  float gma[4], bta[4], c_reg[4];
  #pragma unroll
  for (int g = 0; g < 4; ++g) { gma[g] = gamma[g * O_ + o]; bta[g] = beta[g * O_ + o]; }
  { float c0 = init_cx[o];
    #pragma unroll
    for (int r = 0; r < 4; ++r) c_reg[r] = c0; }

  // ---- zx ring read helper state: lane reads u32 word containing its 2B
  const int wsel = col & 1;            // which half of the u32
  const int widx = col >> 1;           // u32 index within 16-col group

  // ---- prologue: wait for zx chunk 0, then prefetch zx for t=0
  {
    unsigned spins = 0;
    while (__hip_atomic_load(&zxcnt[0], __ATOMIC_RELAXED,
                             __HIP_MEMORY_SCOPE_AGENT) < 64u) {
      __builtin_amdgcn_s_sleep(2);
      if (++spins > BAILOUT) break;
    }
  }
  unsigned short zxl[16];
  #pragma unroll
  for (int g = 0; g < 4; ++g)
    #pragma unroll
    for (int r = 0; r < 4; ++r) {
      int b = 16 * w + 4 * q + r;
      const unsigned* rowp =
          (const unsigned*)(zx + zx_row(b, 0) * NZ + g * O_ + OSL * s);
      unsigned vw = __hip_atomic_load(rowp + widx, __ATOMIC_RELAXED,
                                      __HIP_MEMORY_SCOPE_AGENT);
      zxl[g * 4 + r] = (unsigned short)(wsel ? (vw >> 16) : (vw & 0xffffu));
    }

  __syncthreads();

  for (int t = 0; t < T_; ++t) {
    // ---- gather full h fragment set (sc1 read-through; fresh after bar2)
    unsigned long long araw[32];
    const unsigned short* hrow = h + (16 * w + col) * O_;
    #pragma unroll
    for (int ks = 0; ks < 16; ++ks) {
      const unsigned long long* p =
          (const unsigned long long*)(hrow + ks * 32 + q * 8);
      araw[2 * ks]     = __hip_atomic_load(p,     __ATOMIC_RELAXED, __HIP_MEMORY_SCOPE_AGENT);
      araw[2 * ks + 1] = __hip_atomic_load(p + 1, __ATOMIC_RELAXED, __HIP_MEMORY_SCOPE_AGENT);
    }

    // ---- z-slice = h @ Wh^T  (16x16x32 bf16 MFMA; Wh from LDS)
    f32x4 acc[4];
    #pragma unroll
    for (int g = 0; g < 4; ++g) acc[g] = (f32x4){0.f, 0.f, 0.f, 0.f};

    #pragma unroll
    for (int ks = 0; ks < 16; ++ks) {
      union { unsigned long long u[2]; bf8_t v; } au;
      au.u[0] = araw[2 * ks]; au.u[1] = araw[2 * ks + 1];
      #pragma unroll
      for (int g = 0; g < 4; ++g) {
        bf8_t bfr = *(const bf8_t*)(&whlds[(g * 16 + col) * 520 + ks * 32 + q * 8]);
        acc[g] = __builtin_amdgcn_mfma_f32_16x16x32_bf16(au.v, bfr, acc[g], 0, 0, 0);
      }
    }

    // ---- z = acc + zx; block-partial LN sums per batch row
    float z[16];
    float s1[4], s2[4];
    #pragma unroll
    for (int r = 0; r < 4; ++r) { s1[r] = 0.f; s2[r] = 0.f; }
    #pragma unroll
    for (int g = 0; g < 4; ++g)
      #pragma unroll
      for (int r = 0; r < 4; ++r) {
        float zv = acc[g][r] + bf2f(zxl[g * 4 + r]);
        z[g * 4 + r] = zv;
        s1[r] += zv;
        s2[r] += zv * zv;
      }
    #pragma unroll
    for (int m = 1; m < 16; m <<= 1) {
      #pragma unroll
      for (int r = 0; r < 4; ++r) {
        s1[r] += __shfl_xor(s1[r], m, 64);
        s2[r] += __shfl_xor(s2[r], m, 64);
      }
    }
    if (col == 0) {
      #pragma unroll
      for (int r = 0; r < 4; ++r) {
        int b = 16 * w + 4 * q + r;
        union { float f[2]; unsigned long long u; } pv;
        pv.f[0] = s1[r]; pv.f[1] = s2[r];
        __hip_atomic_store(&part8[(size_t)s * 64 + b], pv.u,
                           __ATOMIC_RELAXED, __HIP_MEMORY_SCOPE_AGENT);
      }
    }

    // ---- barrier 1: partials ready (wave0-only poll + fan-out)
    __syncthreads();   // drains vmcnt(0) for all waves -> partials at LLC
    {
      const unsigned tgt = 2u * (unsigned)t + 1u;
      if (tid == 0)
        __hip_atomic_store(&flags[s * 16], tgt,
                           __ATOMIC_RELAXED, __HIP_MEMORY_SCOPE_AGENT);
      if (tid < 64) {
        const unsigned* fp = &flags[(lane & 31) * 16];
        while (__hip_atomic_load(fp, __ATOMIC_RELAXED, __HIP_MEMORY_SCOPE_AGENT) < tgt)
          __builtin_amdgcn_s_sleep(1);
      }
      __syncthreads();
    }

    // ---- distributed LN reduce: lane owns brow = 16w+(lane&15); 8 s-chunks
    float S1 = 0.f, S2 = 0.f;
    {
      const int brow = 16 * w + (lane & 15);
      const int sbase = (lane >> 4) * 8;
      #pragma unroll
      for (int i = 0; i < 8; ++i) {
        union { float f[2]; unsigned long long u; } pv;
        pv.u = __hip_atomic_load(&part8[(size_t)(sbase + i) * 64 + brow],
                                 __ATOMIC_RELAXED, __HIP_MEMORY_SCOPE_AGENT);
        S1 += pv.f[0]; S2 += pv.f[1];
      }
    }
    S1 += __shfl_xor(S1, 16, 64); S2 += __shfl_xor(S2, 16, 64);
    S1 += __shfl_xor(S1, 32, 64); S2 += __shfl_xor(S2, 32, 64);
    float mean_l = S1 * (1.f / NZ);
    float rstd_l = rsqrtf(S2 * (1.f / NZ) - mean_l * mean_l + EPS);

    // ---- gates + state update (mean/rstd pulled from lane 4q+r)
    float hnl[4];
    #pragma unroll
    for (int r = 0; r < 4; ++r) {
      int b = 16 * w + 4 * q + r;
      float mean = __shfl(mean_l, 4 * q + r, 64);
      float rstd = __shfl(rstd_l, 4 * q + r, 64);
      float zn0 = (z[0 * 4 + r] - mean) * rstd * gma[0] + bta[0];
      float zn1 = (z[1 * 4 + r] - mean) * rstd * gma[1] + bta[1];
      float zn2 = (z[2 * 4 + r] - mean) * rstd * gma[2] + bta[2];
      float zn3 = (z[3 * 4 + r] - mean) * rstd * gma[3] + bta[3];
      float fg = 1.f / (1.f + expf(-zn0));
      float ig = 1.f / (1.f + expf(-zn1));
      float og = 1.f / (1.f + expf(-zn2));
      float gg = 0.5f * zn3 * (1.f + erff(zn3 * 0.70710678118654752f));
      float cn = fg * c_reg[r] + ig * gg;
      float hn = og * cn;
      c_reg[r] = cn;
      hnl[r] = hn;
      __hip_atomic_store(&h[b * O_ + o], f2bf(hn),
                         __ATOMIC_RELAXED, __HIP_MEMORY_SCOPE_AGENT);
    }

    // ---- barrier 2: h ready. out stores + zx prefetch in the shadow;
    //      wave0-only poll; block 0 publishes consumer progress after poll.
    if (t + 1 < T_) {
      __syncthreads();   // drains vmcnt(0) -> h stores at LLC
      const unsigned tgt = 2u * (unsigned)t + 2u;
      if (tid == 0)
        __hip_atomic_store(&flags[s * 16], tgt,
                           __ATOMIC_RELAXED, __HIP_MEMORY_SCOPE_AGENT);
      #pragma unroll
      for (int r = 0; r < 4; ++r) {
        int b = 16 * w + 4 * q + r;
        out[((size_t)b * T_ + t) * O_ + o] = hnl[r];
      }
      // gate on producer chunk at chunk boundaries, then prefetch zx(t+1)
      if (((t + 1) & 63) == 0) {
        const int tc = (t + 1) >> 6;
        unsigned spins = 0;
        while (__hip_atomic_load(&zxcnt[tc], __ATOMIC_RELAXED,
                                 __HIP_MEMORY_SCOPE_AGENT) < 64u) {
          __builtin_amdgcn_s_sleep(2);
          if (++spins > BAILOUT) break;
        }
      }
      #pragma unroll
      for (int g = 0; g < 4; ++g)
        #pragma unroll
        for (int r = 0; r < 4; ++r) {
          int b = 16 * w + 4 * q + r;
          const unsigned* rowp =
              (const unsigned*)(zx + zx_row(b, t + 1) * NZ + g * O_ + OSL * s);
          unsigned vw = __hip_atomic_load(rowp + widx, __ATOMIC_RELAXED,
                                          __HIP_MEMORY_SCOPE_AGENT);
          zxl[g * 4 + r] = (unsigned short)(wsel ? (vw >> 16) : (vw & 0xffffu));
        }
      if (tid < 64) {
        const unsigned* fp = &flags[(lane & 31) * 16];
        while (__hip_atomic_load(fp, __ATOMIC_RELAXED, __HIP_MEMORY_SCOPE_AGENT) < tgt)
          __builtin_amdgcn_s_sleep(1);
      }
      if (s == 0 && tid == 0)
        __hip_atomic_store(progress, tgt,
                           __ATOMIC_RELAXED, __HIP_MEMORY_SCOPE_AGENT);
      __syncthreads();
    } else {
      #pragma unroll
      for (int r = 0; r < 4; ++r) {
        int b = 16 * w + 4 * q + r;
        out[((size_t)b * T_ + t) * O_ + o] = hnl[r];
      }
    }
  }
}

// ---------------------------------------------------------------------------
extern "C" void kernel_launch(void* const* d_in, const int* in_sizes, int n_in,
                              void* d_out, int out_size, void* d_ws, size_t ws_size,
                              hipStream_t stream) {
  const float* x       = (const float*)d_in[0];
  const float* W       = (const float*)d_in[1];
  const float* gamma   = (const float*)d_in[2];
  const float* beta    = (const float*)d_in[3];
  const float* init_hx = (const float*)d_in[4];
  const float* init_cx = (const float*)d_in[5];
  float* out = (float*)d_out;
  (void)in_sizes; (void)n_in; (void)out_size; (void)ws_size;

  char* ws = (char*)d_ws;
  unsigned*           flags = (unsigned*)(ws);                        // 8 KB zeroed (zxcnt@+4KB, progress@+3KB)
  unsigned long long* part8 = (unsigned long long*)(ws + 8192);       // 16 KB
  unsigned short*     h     = (unsigned short*)(ws + 32768);          // 64 KB
  unsigned short*     Wbf   = (unsigned short*)(ws + (1 << 20));      // 2 MB
  unsigned short*     zx    = (unsigned short*)(ws + (4 << 20));      // 64 MB ring

  init_all<<<128, 256, 0, stream>>>(init_hx, h, flags);
  wx_bf16<<<1024, 256, 0, stream>>>(W, Wbf);
  fused_rec<<<SREC + NPROD, 256, 0, stream>>>(x, Wbf, W, gamma, beta, init_cx,
                                              zx, h, part8, out, flags);
}